// Round 18
// baseline (414.597 us; speedup 1.0000x reference)
//
#include <hip/hip_runtime.h>
#include <hip/hip_bf16.h>

typedef __attribute__((ext_vector_type(8))) __bf16 bf16x8;
typedef __attribute__((ext_vector_type(4))) __bf16 bf16x4;
typedef __attribute__((ext_vector_type(4))) float f32x4;

#define MFMA16(a, b, c) __builtin_amdgcn_mfma_f32_16x16x32_bf16((a), (b), (c), 0, 0, 0)

__device__ __forceinline__ void gload_lds16(const void* g, void* l) {
    __builtin_amdgcn_global_load_lds((const __attribute__((address_space(1))) void*)g,
                                     (__attribute__((address_space(3))) void*)l, 16, 0, 0);
}

// XOR-swizzle within each 1KB (16-row) region of a [R][32]bf16 LDS tile (64B rows).
// Measured (r10): SQ_LDS_BANK_CONFLICT 4.2M -> 0.
__device__ __forceinline__ int lds_swz(int r, int ck) {
    int W = ((r & 15) << 6) | (ck << 4);
    W ^= ((W >> 7) & 7) << 4;
    return ((r >> 4) << 9) + (W >> 1);
}

// ---------------- prep: gk1+cvt (blocks 0-2047) and 5 weight transposes (2048-10239) ----------
__global__ __launch_bounds__(256) void prep(
    const float* __restrict__ x, const float* __restrict__ w1,
    float* __restrict__ t, __bf16* __restrict__ xb,
    const float* __restrict__ Wq, const float* __restrict__ Wk,
    const float* __restrict__ Wg, const float* __restrict__ Wv,
    const float* __restrict__ Wo, __bf16* __restrict__ WTqk,
    __bf16* __restrict__ WTg, __bf16* __restrict__ WvT, __bf16* __restrict__ WoT) {
    __shared__ float tile[32][33];
    if (blockIdx.x < 2048) {
        const int row = blockIdx.x * 4 + (threadIdx.x >> 6);
        const int l = threadIdx.x & 63;
        const int r = l & 15, kg = l >> 4;
        const float* xr = x + (size_t)row * 1024;
        const float* w1p = w1 + r;
        float acc = 0.f;
        for (int k = kg * 256; k < (kg + 1) * 256; ++k) acc = fmaf(xr[k], w1p[k * 16], acc);
        acc += __shfl_xor(acc, 16);
        acc += __shfl_xor(acc, 32);
        if (kg == 0) t[(size_t)row * 16 + r] = acc;

        const size_t base = (size_t)blockIdx.x * 4096 + threadIdx.x * 16;
#pragma unroll
        for (int v = 0; v < 4; v++) {
            f32x4 f = *(const f32x4*)(x + base + v * 4);
            bf16x4 o;
#pragma unroll
            for (int j = 0; j < 4; j++) o[j] = (__bf16)f[j];
            *(bf16x4*)(xb + base + v * 4) = o;
        }
        return;
    }
    const int bid = blockIdx.x - 2048;
    const float* in;
    __bf16* out;
    int R, C, loc, gw;
    if (bid < 1024)      { in = Wq; out = WTqk;            R = 1024; C = 1024; loc = bid;        gw = 32; }
    else if (bid < 2048) { in = Wk; out = WTqk + 1048576;  R = 1024; C = 1024; loc = bid - 1024; gw = 32; }
    else if (bid < 4096) { in = Wg; out = WTg;             R = 1024; C = 2048; loc = bid - 2048; gw = 64; }
    else if (bid < 6144) { in = Wv; out = WvT;             R = 1024; C = 2048; loc = bid - 4096; gw = 64; }
    else                 { in = Wo; out = WoT;             R = 2048; C = 1024; loc = bid - 6144; gw = 32; }
    const int c0 = (loc % gw) * 32, r0 = (loc / gw) * 32;
    const int tx = threadIdx.x & 31, ty = threadIdx.x >> 5;
#pragma unroll
    for (int k = 0; k < 32; k += 8)
        tile[ty + k][tx] = in[(size_t)(r0 + ty + k) * C + c0 + tx];
    __syncthreads();
#pragma unroll
    for (int k = 0; k < 32; k += 8)
        out[(size_t)(c0 + ty + k) * R + r0 + tx] = (__bf16)tile[tx][ty + k];
}

// ---------------- merged projections: qkg (2048 blocks) + vt (1024 blocks) ----------------
__global__ __launch_bounds__(256) void gemm_proj(const __bf16* __restrict__ xb,
                                                 const __bf16* __restrict__ WT,
                                                 const __bf16* __restrict__ WvT,
                                                 __bf16* __restrict__ Cq,
                                                 __bf16* __restrict__ Cg,
                                                 __bf16* __restrict__ vt) {
    constexpr int K = 1024;
    __shared__ alignas(16) __bf16 As[2][4096];
    __shared__ alignas(16) __bf16 Bs[2][4096];
    const int tid = threadIdx.x;
    const int wv = tid >> 6;
    const int l = tid & 63;
    const int bid = blockIdx.x;
    const int wg = (bid & 7) * 384 + (bid >> 3);  // 3072 blocks, XCD swizzle
    const int mode = (wg >= 2048);
    int bm, bn;
    const __bf16 *Ab, *Bb;
    if (!mode) {
        bm = wg >> 5; bn = wg & 31;
        Ab = xb + (size_t)bm * 128 * K;
        Bb = WT + (size_t)bn * 128 * K;
    } else {
        const int w2 = wg - 2048;
        bm = w2 >> 6; bn = w2 & 63;
        Ab = WvT + (size_t)bm * 128 * K;
        Bb = xb + (size_t)bn * 128 * K;
    }
    const int L = (l << 4) ^ ((l >> 3) << 4);
    const int sr = L >> 6;
    const int sc8 = ((L >> 4) & 3) * 8;
    const int lr = tid & 15;
    const int ck = (tid >> 4) & 3;
    const int wm = (wv >> 1) * 64, wn = (wv & 1) * 64;

    auto STAGE = [&](int buf, int kt) {
        gload_lds16(Ab + (size_t)(wv * 16 + sr) * K + kt + sc8, &As[buf][0] + wv * 512);
        gload_lds16(Ab + (size_t)(64 + wv * 16 + sr) * K + kt + sc8, &As[buf][0] + 2048 + wv * 512);
        gload_lds16(Bb + (size_t)(wv * 16 + sr) * K + kt + sc8, &Bs[buf][0] + wv * 512);
        gload_lds16(Bb + (size_t)(64 + wv * 16 + sr) * K + kt + sc8, &Bs[buf][0] + 2048 + wv * 512);
    };

    const int nt = K >> 5;
    STAGE(0, 0);

    f32x4 acc[4][4] = {};
    for (int t = 0; t < nt; ++t) {
        __builtin_amdgcn_s_barrier();
        __builtin_amdgcn_sched_barrier(0);
        if (t + 1 < nt) {
            STAGE((t + 1) & 1, (t + 1) * 32);
            asm volatile("s_waitcnt vmcnt(4)" ::: "memory");
        } else {
            asm volatile("s_waitcnt vmcnt(0)" ::: "memory");
        }
        __builtin_amdgcn_sched_barrier(0);
        const __bf16* as = &As[t & 1][0];
        const __bf16* bs = &Bs[t & 1][0];
        bf16x8 af[4], bfr[4];
#pragma unroll
        for (int i = 0; i < 4; i++) af[i] = *(const bf16x8*)(as + lds_swz(wm + i * 16 + lr, ck));
#pragma unroll
        for (int j = 0; j < 4; j++) bfr[j] = *(const bf16x8*)(bs + lds_swz(wn + j * 16 + lr, ck));
#pragma unroll
        for (int i = 0; i < 4; i++)
#pragma unroll
            for (int j = 0; j < 4; j++) acc[i][j] = MFMA16(af[i], bfr[j], acc[i][j]);
        asm volatile("s_waitcnt lgkmcnt(0)" ::: "memory");
    }
    const int lro = ((tid >> 4) & 3) * 4;
    if (!mode) {
        __bf16* Cd = (bn < 16) ? Cq : Cg;
        const int col0 = (bn & 15) * 128;
#pragma unroll
        for (int i = 0; i < 4; i++)
#pragma unroll
            for (int j = 0; j < 4; j++) {
                size_t base = (size_t)(bm * 128 + wm + i * 16 + lro) * 2048 + col0 + wn + j * 16 + lr;
#pragma unroll
                for (int r = 0; r < 4; r++) Cd[base + (size_t)r * 2048] = (__bf16)acc[i][j][r];
            }
    } else {
#pragma unroll
        for (int i = 0; i < 4; i++)
#pragma unroll
            for (int j = 0; j < 4; j++) {
                size_t base = (size_t)(bm * 128 + wm + i * 16 + lro) * 8192 + bn * 128 + wn + j * 16 + lr;
#pragma unroll
                for (int r = 0; r < 4; r++) vt[base + (size_t)r * 8192] = (__bf16)acc[i][j][r];
            }
    }
}

// ---------------- Wo GEMM, split-K=2: out += gated @ WoT^T per K-half (atomicAdd f32) ----------
// grid 1024 = tile(512: 64 bm x 8 bn) x kh(2). Deterministic: exactly 2 commutative adds onto 0.
__global__ __launch_bounds__(256) void gemm_wo(const __bf16* __restrict__ A,
                                               const __bf16* __restrict__ Bt,
                                               float* __restrict__ C) {
    constexpr int K = 2048, KH = 1024, N = 1024;
    __shared__ alignas(16) __bf16 As[2][4096];
    __shared__ alignas(16) __bf16 Bs[2][4096];
    const int tid = threadIdx.x;
    const int wv = tid >> 6;
    const int l = tid & 63;
    const int bid = blockIdx.x;
    const int wg = (bid & 7) * 128 + (bid >> 3);  // 1024 blocks
    const int kh = wg >> 9, tile = wg & 511;
    const int bm = tile >> 3, bn = tile & 7;

    const __bf16* Ab = A + (size_t)bm * 128 * K + kh * KH;
    const __bf16* Bb = Bt + (size_t)bn * 128 * K + kh * KH;
    const int L = (l << 4) ^ ((l >> 3) << 4);
    const int sr = L >> 6;
    const int sc8 = ((L >> 4) & 3) * 8;
    const int lr = tid & 15;
    const int ck = (tid >> 4) & 3;
    const int wm = (wv >> 1) * 64, wn = (wv & 1) * 64;

    auto STAGE = [&](int buf, int kt) {
        gload_lds16(Ab + (size_t)(wv * 16 + sr) * K + kt + sc8, &As[buf][0] + wv * 512);
        gload_lds16(Ab + (size_t)(64 + wv * 16 + sr) * K + kt + sc8, &As[buf][0] + 2048 + wv * 512);
        gload_lds16(Bb + (size_t)(wv * 16 + sr) * K + kt + sc8, &Bs[buf][0] + wv * 512);
        gload_lds16(Bb + (size_t)(64 + wv * 16 + sr) * K + kt + sc8, &Bs[buf][0] + 2048 + wv * 512);
    };

    const int nt = KH >> 5;  // 32
    STAGE(0, 0);

    f32x4 acc[4][4] = {};
    for (int t = 0; t < nt; ++t) {
        __builtin_amdgcn_s_barrier();
        __builtin_amdgcn_sched_barrier(0);
        if (t + 1 < nt) {
            STAGE((t + 1) & 1, (t + 1) * 32);
            asm volatile("s_waitcnt vmcnt(4)" ::: "memory");
        } else {
            asm volatile("s_waitcnt vmcnt(0)" ::: "memory");
        }
        __builtin_amdgcn_sched_barrier(0);
        const __bf16* as = &As[t & 1][0];
        const __bf16* bs = &Bs[t & 1][0];
        bf16x8 af[4], bfr[4];
#pragma unroll
        for (int i = 0; i < 4; i++) af[i] = *(const bf16x8*)(as + lds_swz(wm + i * 16 + lr, ck));
#pragma unroll
        for (int j = 0; j < 4; j++) bfr[j] = *(const bf16x8*)(bs + lds_swz(wn + j * 16 + lr, ck));
#pragma unroll
        for (int i = 0; i < 4; i++)
#pragma unroll
            for (int j = 0; j < 4; j++) acc[i][j] = MFMA16(af[i], bfr[j], acc[i][j]);
        asm volatile("s_waitcnt lgkmcnt(0)" ::: "memory");
    }
    const int lro = ((tid >> 4) & 3) * 4;
#pragma unroll
    for (int i = 0; i < 4; i++)
#pragma unroll
        for (int j = 0; j < 4; j++) {
            size_t base = (size_t)(bm * 128 + wm + i * 16 + lro) * N + bn * 128 + wn + j * 16 + lr;
#pragma unroll
            for (int r = 0; r < 4; r++) atomicAdd(&C[base + (size_t)r * N], acc[i][j][r]);
        }
}

// ---------------- per-(b,h,chunk128): gates, qg, kg, kgT, e^blast ----------------
__global__ __launch_bounds__(1024, 4) void gate_qkg(
    const float* __restrict__ tbuf, const float* __restrict__ w2,
    const float* __restrict__ b2, const __bf16* __restrict__ qkbuf,
    __bf16* __restrict__ qg, __bf16* __restrict__ kg,
    __bf16* __restrict__ kgT, float* __restrict__ ebl) {
    __shared__ alignas(16) float t_l[128 * 16];
    __shared__ float qs[4 * 256];
    __shared__ __bf16 kg_l[128 * 260];
    const int bid = blockIdx.x;
    const int bh = bid & 15, nc = bid >> 4;
    const int b = bh >> 2, h = bh & 3;
    const int tid = threadIdx.x;
    const int d = tid & 255, cq = tid >> 8;
    const int seq0 = b * 2048 + nc * 128;
    const int hd = h * 256 + d;

    for (int i = tid; i < 128 * 16; i += 1024) t_l[i] = tbuf[(size_t)seq0 * 16 + i];
    float w2c[16];
#pragma unroll
    for (int r = 0; r < 16; r++) w2c[r] = w2[r * 1024 + hd];
    const float b2v = b2[hd];
    __syncthreads();

    float bs[32];
    float run = 0.f;
#pragma unroll
    for (int j = 0; j < 32; j++) {
        const int c = cq * 32 + j;
        f32x4 t0 = *(const f32x4*)(t_l + c * 16);
        f32x4 t1 = *(const f32x4*)(t_l + c * 16 + 4);
        f32x4 t2 = *(const f32x4*)(t_l + c * 16 + 8);
        f32x4 t3 = *(const f32x4*)(t_l + c * 16 + 12);
        float u = b2v;
#pragma unroll
        for (int r = 0; r < 4; r++) {
            u = fmaf(t0[r], w2c[r], u);
            u = fmaf(t1[r], w2c[4 + r], u);
            u = fmaf(t2[r], w2c[8 + r], u);
            u = fmaf(t3[r], w2c[12 + r], u);
        }
        const float ls = fminf(u, 0.f) - __logf(1.f + __expf(-fabsf(u)));
        run += ls * 0.0625f;
        bs[j] = run;
    }
    qs[cq * 256 + d] = run;
    __syncthreads();

    float prefix = 0.f;
#pragma unroll
    for (int q = 0; q < 3; q++)
        if (q < cq) prefix += qs[q * 256 + d];

#pragma unroll
    for (int j = 0; j < 32; j++) {
        const int c = cq * 32 + j;
        const float bsum = prefix + bs[j];
        const float eb = __expf(bsum);
        const float en = __expf(-bsum);
        const float qv = (float)qkbuf[(size_t)(seq0 + c) * 2048 + hd];
        const float kv = (float)qkbuf[(size_t)(seq0 + c) * 2048 + 1024 + hd];
        qg[(size_t)(seq0 + c) * 1024 + hd] = (__bf16)(qv * eb * 0.0625f);
        const __bf16 kgv = (__bf16)(kv * en);
        kg[(size_t)(seq0 + c) * 1024 + hd] = kgv;
        kg_l[c * 260 + d] = kgv;
    }
    if (cq == 3) ebl[(size_t)(nc * 16 + bh) * 256 + d] = __expf(prefix + bs[31]);
    __syncthreads();

    {
        const int cc = tid & 127, dgroup = tid >> 7;
        for (int i = 0; i < 32; i++) {
            const int dd = dgroup * 32 + i;
            kgT[(size_t)(bh * 256 + dd) * 2048 + nc * 128 + cc] = kg_l[cc * 260 + dd];
        }
    }
}

// ---------------- merged: a_mat (blocks 0-255) + chunk_u (blocks 256-1279) ----------------
__global__ __launch_bounds__(512) void amat_chunku(
    const __bf16* __restrict__ qg, const __bf16* __restrict__ kg,
    __bf16* __restrict__ Abuf, const __bf16* __restrict__ vt,
    const __bf16* __restrict__ kgT, __bf16* __restrict__ UH) {
    const int tid = threadIdx.x, wv = tid >> 6, l = tid & 63;
    const int lr = l & 15, lk = (l >> 4) * 8, lro = (l >> 4) * 4;
    if (blockIdx.x < 256) {
        const int pair = blockIdx.x;
        const int bh = pair & 15, nc = pair >> 4;
        const int b = bh >> 2, h = bh & 3;
        const int seq0 = b * 2048 + nc * 128;
        __bf16* Ab = Abuf + (size_t)pair * 16384;
        {
            bf16x8 z = {};
            for (int i = tid; i < 2048; i += 512) *(bf16x8*)(Ab + (size_t)i * 8) = z;
        }
        __syncthreads();
        static const int TJ[36] = {0,1,1,2,2,2,3,3,3,3,4,4,4,4,4,5,5,5,5,5,5,
                                   6,6,6,6,6,6,6,7,7,7,7,7,7,7,7};
        static const int TS[36] = {0,0,1,0,1,2,0,1,2,3,0,1,2,3,4,0,1,2,3,4,5,
                                   0,1,2,3,4,5,6,0,1,2,3,4,5,6,7};
        for (int m = wv; m < 36; m += 8) {
            const int j = TJ[m], s = TS[m];
            f32x4 acc = {};
            const __bf16* qrow = qg + (size_t)(seq0 + j * 16 + lr) * 1024 + h * 256;
            const __bf16* krow = kg + (size_t)(seq0 + s * 16 + lr) * 1024 + h * 256;
#pragma unroll
            for (int ks = 0; ks < 8; ks++) {
                bf16x8 a = *(const bf16x8*)(qrow + ks * 32 + lk);
                bf16x8 bb = *(const bf16x8*)(krow + ks * 32 + lk);
                acc = MFMA16(a, bb, acc);
            }
#pragma unroll
            for (int r = 0; r < 4; r++) {
                const int t = j * 16 + lro + r;
                const int ss = s * 16 + lr;
                if (ss <= t) Ab[t * 128 + ss] = (__bf16)acc[r];
            }
        }
    } else {
        const int bid = blockIdx.x - 256;
        const int bh = bid & 15, nc = (bid >> 4) & 15, q = bid >> 8;
        const int eh = q >> 1, dh = q & 1;
        const int b = bh >> 2, h = bh & 3;
        const int seq0 = b * 2048 + nc * 128;
        const int e0 = eh * 256 + (wv >> 1) * 64;
        const int d0 = dh * 128 + (wv & 1) * 64;
        const __bf16* va = vt + (size_t)(h * 512 + e0) * 8192 + seq0;
        const __bf16* kb = kgT + (size_t)(bh * 256 + d0) * 2048 + nc * 128;

        f32x4 acc[4][4] = {};
#pragma unroll
        for (int ks = 0; ks < 4; ks++) {
            bf16x8 af[4], bf_[4];
#pragma unroll
            for (int i = 0; i < 4; i++)
                af[i] = *(const bf16x8*)(va + (size_t)(i * 16 + lr) * 8192 + ks * 32 + lk);
#pragma unroll
            for (int j = 0; j < 4; j++)
                bf_[j] = *(const bf16x8*)(kb + (size_t)(j * 16 + lr) * 2048 + ks * 32 + lk);
#pragma unroll
            for (int i = 0; i < 4; i++)
#pragma unroll
                for (int j = 0; j < 4; j++) acc[i][j] = MFMA16(af[i], bf_[j], acc[i][j]);
        }
        __bf16* ub = UH + ((size_t)(nc * 16 + bh) * 512 + e0) * 256 + d0;
#pragma unroll
        for (int i = 0; i < 4; i++)
#pragma unroll
            for (int j = 0; j < 4; j++)
#pragma unroll
                for (int r = 0; r < 4; r++)
                    ub[(size_t)(i * 16 + lro + r) * 256 + j * 16 + lr] = (__bf16)acc[i][j][r];
    }
}

// ---------------- ointer: o = [A|qg] @ [vt_slice | H_slot]^T (r12 pipeline) ----------------
__global__ __launch_bounds__(256) void ointer(
    const __bf16* __restrict__ Abuf, const __bf16* __restrict__ qg,
    const __bf16* __restrict__ vt, const __bf16* __restrict__ UH,
    __bf16* __restrict__ ob) {
    __shared__ alignas(16) __bf16 As[2][4096];
    __shared__ alignas(16) __bf16 Bs[2][4096];
    const int tid = threadIdx.x;
    const int wv = tid >> 6;
    const int l = tid & 63;
    const int bid = blockIdx.x;
    const int wg = (bid & 7) * 128 + (bid >> 3);
    const int bn = wg & 3, pair = wg >> 2;
    const int bh = pair & 15, nc = pair >> 4;
    const int b = bh >> 2, h = bh & 3;
    const int seq0 = b * 2048 + nc * 128;
    const int L = (l << 4) ^ ((l >> 3) << 4);
    const int sr = L >> 6;
    const int sc8 = ((L >> 4) & 3) * 8;
    const int lr = tid & 15;
    const int ck = (tid >> 4) & 3;
    const int wm = (wv >> 1) * 64, wn = (wv & 1) * 64;
    const int KE = (nc == 0) ? 128 : 384;

    const __bf16* Ap = Abuf + (size_t)pair * 16384;
    const __bf16* Hb = UH + ((size_t)((nc - 1) * 16 + bh) * 512 + bn * 128) * 256;

    auto STAGE = [&](int buf, int kt) {
        const __bf16 *a0, *a1, *b0, *b1;
        if (kt < 128) {
            a0 = Ap + (size_t)(wv * 16 + sr) * 128 + kt + sc8;
            a1 = Ap + (size_t)(64 + wv * 16 + sr) * 128 + kt + sc8;
            b0 = vt + (size_t)(h * 512 + bn * 128 + wv * 16 + sr) * 8192 + seq0 + kt + sc8;
            b1 = vt + (size_t)(h * 512 + bn * 128 + 64 + wv * 16 + sr) * 8192 + seq0 + kt + sc8;
        } else {
            const int kd = kt - 128;
            a0 = qg + (size_t)(seq0 + wv * 16 + sr) * 1024 + h * 256 + kd + sc8;
            a1 = qg + (size_t)(seq0 + 64 + wv * 16 + sr) * 1024 + h * 256 + kd + sc8;
            b0 = Hb + (size_t)(wv * 16 + sr) * 256 + kd + sc8;
            b1 = Hb + (size_t)(64 + wv * 16 + sr) * 256 + kd + sc8;
        }
        gload_lds16(a0, &As[buf][0] + wv * 512);
        gload_lds16(a1, &As[buf][0] + 2048 + wv * 512);
        gload_lds16(b0, &Bs[buf][0] + wv * 512);
        gload_lds16(b1, &Bs[buf][0] + 2048 + wv * 512);
    };

    const int nt = KE >> 5;
    STAGE(0, 0);

    f32x4 acc[4][4] = {};
    for (int t = 0; t < nt; ++t) {
        __builtin_amdgcn_s_barrier();
        __builtin_amdgcn_sched_barrier(0);
        if (t + 1 < nt) {
            STAGE((t + 1) & 1, (t + 1) * 32);
            asm volatile("s_waitcnt vmcnt(4)" ::: "memory");
        } else {
            asm volatile("s_waitcnt vmcnt(0)" ::: "memory");
        }
        __builtin_amdgcn_sched_barrier(0);
        const __bf16* as = &As[t & 1][0];
        const __bf16* bs = &Bs[t & 1][0];
        bf16x8 af[4], bfr[4];
#pragma unroll
        for (int i = 0; i < 4; i++) af[i] = *(const bf16x8*)(as + lds_swz(wm + i * 16 + lr, ck));
#pragma unroll
        for (int j = 0; j < 4; j++) bfr[j] = *(const bf16x8*)(bs + lds_swz(wn + j * 16 + lr, ck));
#pragma unroll
        for (int i = 0; i < 4; i++)
#pragma unroll
            for (int j = 0; j < 4; j++) acc[i][j] = MFMA16(af[i], bfr[j], acc[i][j]);
        asm volatile("s_waitcnt lgkmcnt(0)" ::: "memory");
    }
    const int lro = ((tid >> 4) & 3) * 4;
#pragma unroll
    for (int i = 0; i < 4; i++)
#pragma unroll
        for (int j = 0; j < 4; j++) {
            size_t base = (size_t)(seq0 + wm + i * 16 + lro) * 2048 + h * 512 + bn * 128 + wn + j * 16 + lr;
#pragma unroll
            for (int r = 0; r < 4; r++) ob[base + (size_t)r * 2048] = (__bf16)acc[i][j][r];
        }
}

// ---------------- hscan: in-place elementwise scan over 16 chunk slots ----------------
__global__ __launch_bounds__(256) void hscan(__bf16* __restrict__ UH,
                                             const float* __restrict__ ebl) {
    const int t = blockIdx.x * 256 + threadIdx.x;
    const int bh = t >> 14;
    const int rem = t & 16383;
    const int e = rem >> 5, d0 = (rem & 31) * 8;
    float H[8];
#pragma unroll
    for (int j = 0; j < 8; j++) H[j] = 0.f;
    for (int i = 0; i < 16; i++) {
        size_t idx = ((size_t)(i * 16 + bh) * 512 + e) * 256 + d0;
        bf16x8 u = *(const bf16x8*)(UH + idx);
        const float* ep = ebl + (size_t)(i * 16 + bh) * 256 + d0;
        f32x4 e0v = *(const f32x4*)ep;
        f32x4 e1v = *(const f32x4*)(ep + 4);
        bf16x8 hw;
#pragma unroll
        for (int j = 0; j < 4; j++) {
            H[j] = e0v[j] * (H[j] + (float)u[j]);
            hw[j] = (__bf16)H[j];
        }
#pragma unroll
        for (int j = 4; j < 8; j++) {
            H[j] = e1v[j - 4] * (H[j] + (float)u[j]);
            hw[j] = (__bf16)H[j];
        }
        *(bf16x8*)(UH + idx) = hw;
    }
}

// ---------------- RMS norm over dv=512 + SiLU gating ----------------
__global__ __launch_bounds__(256) void rms_gate(const __bf16* __restrict__ ob,
                                                const __bf16* __restrict__ gbuf,
                                                const float* __restrict__ gnw,
                                                __bf16* __restrict__ gated) {
    const int idx = blockIdx.x * 4 + (threadIdx.x >> 6);
    const int seq = idx >> 2, h = idx & 3;
    const int l = threadIdx.x & 63;
    bf16x8 o1 = *(const bf16x8*)(ob + (size_t)seq * 2048 + h * 512 + l * 8);
    float v[8];
    float ms = 0.f;
#pragma unroll
    for (int j = 0; j < 8; j++) {
        v[j] = (float)o1[j];
        ms += v[j] * v[j];
    }
#pragma unroll
    for (int off = 1; off < 64; off <<= 1) ms += __shfl_xor(ms, off);
    const float rinv = rsqrtf(ms * (1.f / 512.f) + 1e-5f);
    bf16x8 gv = *(const bf16x8*)(gbuf + (size_t)seq * 2048 + h * 512 + l * 8);
    const float* gw = gnw + l * 8;
    bf16x8 outv;
#pragma unroll
    for (int j = 0; j < 8; j++) {
        float g = (float)gv[j];
        float sig = 1.f / (1.f + expf(-g));
        outv[j] = (__bf16)(v[j] * rinv * gw[j] * g * sig);
    }
    *(bf16x8*)(gated + (size_t)seq * 2048 + h * 512 + l * 8) = outv;
}

extern "C" void kernel_launch(void* const* d_in, const int* in_sizes, int n_in,
                              void* d_out, int out_size, void* d_ws, size_t ws_size,
                              hipStream_t stream) {
    const float* x = (const float*)d_in[0];
    const float* Wq = (const float*)d_in[1];
    const float* Wk = (const float*)d_in[2];
    const float* Wv = (const float*)d_in[3];
    const float* Wg = (const float*)d_in[4];
    const float* w1 = (const float*)d_in[5];
    const float* w2 = (const float*)d_in[6];
    const float* b2 = (const float*)d_in[7];
    const float* gnw = (const float*)d_in[8];
    const float* Wo = (const float*)d_in[9];
    float* out = (float*)d_out;

    char* p = (char*)d_ws;
    auto nxt = [&](size_t bytes) {
        char* r = p;
        p += (bytes + 255) & ~(size_t)255;
        return r;
    };
    __bf16* xb = (__bf16*)nxt(8192ull * 1024 * 2);
    __bf16* WTqk = (__bf16*)nxt(2048ull * 1024 * 2);
    __bf16* WTg = (__bf16*)nxt(2048ull * 1024 * 2);
    __bf16* WvT = (__bf16*)nxt(2048ull * 1024 * 2);
    __bf16* WoT = (__bf16*)nxt(1024ull * 2048 * 2);
    __bf16* gbuf = (__bf16*)nxt(8192ull * 2048 * 2);
    __bf16* vt = (__bf16*)nxt(2048ull * 8192 * 2);
    float* tbuf = (float*)nxt(8192ull * 16 * 4);
    __bf16* qg = (__bf16*)nxt(8192ull * 1024 * 2);
    __bf16* kgT = (__bf16*)nxt(16ull * 256 * 2048 * 2);
    float* ebl = (float*)nxt(16ull * 16 * 256 * 4);
    __bf16* ob = (__bf16*)nxt(8192ull * 2048 * 2);
    __bf16* UH = (__bf16*)nxt(16ull * 16 * 512 * 256 * 2);
    __bf16* kg = xb;        // alias: xb dead before gate_qkg writes kg
    __bf16* qkbuf = UH;     // alias: dead before amat_chunku writes UH
    __bf16* gated = UH;     // alias: UH dead (read by ointer) before rms_gate writes gated
    __bf16* Abuf = WTqk;    // alias: 8MB = WTqk+WTg, both dead before amat_chunku

    prep<<<10240, 256, 0, stream>>>(x, w1, tbuf, xb, Wq, Wk, Wg, Wv, Wo, WTqk, WTg, WvT, WoT);
    gemm_proj<<<3072, 256, 0, stream>>>(xb, WTqk, WvT, qkbuf, gbuf, vt);
    gate_qkg<<<256, 1024, 0, stream>>>(tbuf, w2, b2, qkbuf, qg, kg, kgT, ebl);
    amat_chunku<<<1280, 512, 0, stream>>>(qg, kg, Abuf, vt, kgT, UH);
    hscan<<<1024, 256, 0, stream>>>(UH, ebl);
    ointer<<<1024, 256, 0, stream>>>(Abuf, qg, vt, UH, ob);
    rms_gate<<<8192, 256, 0, stream>>>(ob, gbuf, gnw, gated);
    hipMemsetAsync(out, 0, 8192ull * 1024 * 4, stream);
    gemm_wo<<<1024, 256, 0, stream>>>(gated, WoT, out);
}

// Round 19
// 373.205 us; speedup vs baseline: 1.1109x; 1.1109x over previous
//
#include <hip/hip_runtime.h>
#include <hip/hip_bf16.h>

typedef __attribute__((ext_vector_type(8))) __bf16 bf16x8;
typedef __attribute__((ext_vector_type(4))) __bf16 bf16x4;
typedef __attribute__((ext_vector_type(4))) float f32x4;

#define MFMA16(a, b, c) __builtin_amdgcn_mfma_f32_16x16x32_bf16((a), (b), (c), 0, 0, 0)

__device__ __forceinline__ void gload_lds16(const void* g, void* l) {
    __builtin_amdgcn_global_load_lds((const __attribute__((address_space(1))) void*)g,
                                     (__attribute__((address_space(3))) void*)l, 16, 0, 0);
}

// XOR-swizzle within each 1KB (16-row) region of a [R][32]bf16 LDS tile (64B rows).
// Measured (r10): SQ_LDS_BANK_CONFLICT 4.2M -> 0.
__device__ __forceinline__ int lds_swz(int r, int ck) {
    int W = ((r & 15) << 6) | (ck << 4);
    W ^= ((W >> 7) & 7) << 4;
    return ((r >> 4) << 9) + (W >> 1);
}

// ---------------- prep: gk1+cvt (blocks 0-2047) and 5 weight transposes (2048-10239) ----------
__global__ __launch_bounds__(256) void prep(
    const float* __restrict__ x, const float* __restrict__ w1,
    float* __restrict__ t, __bf16* __restrict__ xb,
    const float* __restrict__ Wq, const float* __restrict__ Wk,
    const float* __restrict__ Wg, const float* __restrict__ Wv,
    const float* __restrict__ Wo, __bf16* __restrict__ WTqk,
    __bf16* __restrict__ WTg, __bf16* __restrict__ WvT, __bf16* __restrict__ WoT) {
    __shared__ float tile[32][33];
    if (blockIdx.x < 2048) {
        const int row = blockIdx.x * 4 + (threadIdx.x >> 6);
        const int l = threadIdx.x & 63;
        const int r = l & 15, kg = l >> 4;
        const float* xr = x + (size_t)row * 1024;
        const float* w1p = w1 + r;
        float acc = 0.f;
        for (int k = kg * 256; k < (kg + 1) * 256; ++k) acc = fmaf(xr[k], w1p[k * 16], acc);
        acc += __shfl_xor(acc, 16);
        acc += __shfl_xor(acc, 32);
        if (kg == 0) t[(size_t)row * 16 + r] = acc;

        const size_t base = (size_t)blockIdx.x * 4096 + threadIdx.x * 16;
#pragma unroll
        for (int v = 0; v < 4; v++) {
            f32x4 f = *(const f32x4*)(x + base + v * 4);
            bf16x4 o;
#pragma unroll
            for (int j = 0; j < 4; j++) o[j] = (__bf16)f[j];
            *(bf16x4*)(xb + base + v * 4) = o;
        }
        return;
    }
    const int bid = blockIdx.x - 2048;
    const float* in;
    __bf16* out;
    int R, C, loc, gw;
    if (bid < 1024)      { in = Wq; out = WTqk;            R = 1024; C = 1024; loc = bid;        gw = 32; }
    else if (bid < 2048) { in = Wk; out = WTqk + 1048576;  R = 1024; C = 1024; loc = bid - 1024; gw = 32; }
    else if (bid < 4096) { in = Wg; out = WTg;             R = 1024; C = 2048; loc = bid - 2048; gw = 64; }
    else if (bid < 6144) { in = Wv; out = WvT;             R = 1024; C = 2048; loc = bid - 4096; gw = 64; }
    else                 { in = Wo; out = WoT;             R = 2048; C = 1024; loc = bid - 6144; gw = 32; }
    const int c0 = (loc % gw) * 32, r0 = (loc / gw) * 32;
    const int tx = threadIdx.x & 31, ty = threadIdx.x >> 5;
#pragma unroll
    for (int k = 0; k < 32; k += 8)
        tile[ty + k][tx] = in[(size_t)(r0 + ty + k) * C + c0 + tx];
    __syncthreads();
#pragma unroll
    for (int k = 0; k < 32; k += 8)
        out[(size_t)(c0 + ty + k) * R + r0 + tx] = (__bf16)tile[tx][ty + k];
}

// ---------------- GEMM: C(M,N) = A(M,K)bf16 @ Bt(N,K)bf16^T (r12 pipeline) ----------------
template <typename OUT_T>
__global__ __launch_bounds__(256) void gemm_bt(const __bf16* __restrict__ A,
                                               const __bf16* __restrict__ Bt,
                                               OUT_T* __restrict__ C, int M, int N, int K) {
    __shared__ alignas(16) __bf16 As[2][4096];
    __shared__ alignas(16) __bf16 Bs[2][4096];
    const int tid = threadIdx.x;
    const int wv = tid >> 6;
    const int l = tid & 63;
    const int nwg = gridDim.x;
    const int cpx = nwg >> 3;
    const int bid = blockIdx.x;
    const int wg = (bid & 7) * cpx + (bid >> 3);
    const int nbn = N >> 7;
    const int bm = wg / nbn, bn = wg - bm * nbn;

    const __bf16* Ab = A + (size_t)bm * 128 * K;
    const __bf16* Bb = Bt + (size_t)bn * 128 * K;
    const int L = (l << 4) ^ ((l >> 3) << 4);
    const int sr = L >> 6;
    const int sc8 = ((L >> 4) & 3) * 8;
    const int lr = tid & 15;
    const int ck = (tid >> 4) & 3;
    const int wm = (wv >> 1) * 64, wn = (wv & 1) * 64;

    auto STAGE = [&](int buf, int kt) {
        gload_lds16(Ab + (size_t)(wv * 16 + sr) * K + kt + sc8, &As[buf][0] + wv * 512);
        gload_lds16(Ab + (size_t)(64 + wv * 16 + sr) * K + kt + sc8, &As[buf][0] + 2048 + wv * 512);
        gload_lds16(Bb + (size_t)(wv * 16 + sr) * K + kt + sc8, &Bs[buf][0] + wv * 512);
        gload_lds16(Bb + (size_t)(64 + wv * 16 + sr) * K + kt + sc8, &Bs[buf][0] + 2048 + wv * 512);
    };

    const int nt = K >> 5;
    STAGE(0, 0);

    f32x4 acc[4][4] = {};
    for (int t = 0; t < nt; ++t) {
        __builtin_amdgcn_s_barrier();
        __builtin_amdgcn_sched_barrier(0);
        if (t + 1 < nt) {
            STAGE((t + 1) & 1, (t + 1) * 32);
            asm volatile("s_waitcnt vmcnt(4)" ::: "memory");
        } else {
            asm volatile("s_waitcnt vmcnt(0)" ::: "memory");
        }
        __builtin_amdgcn_sched_barrier(0);
        const __bf16* as = &As[t & 1][0];
        const __bf16* bs = &Bs[t & 1][0];
        bf16x8 af[4], bfr[4];
#pragma unroll
        for (int i = 0; i < 4; i++) af[i] = *(const bf16x8*)(as + lds_swz(wm + i * 16 + lr, ck));
#pragma unroll
        for (int j = 0; j < 4; j++) bfr[j] = *(const bf16x8*)(bs + lds_swz(wn + j * 16 + lr, ck));
#pragma unroll
        for (int i = 0; i < 4; i++)
#pragma unroll
            for (int j = 0; j < 4; j++) acc[i][j] = MFMA16(af[i], bfr[j], acc[i][j]);
        asm volatile("s_waitcnt lgkmcnt(0)" ::: "memory");
    }
    const int lro = ((tid >> 4) & 3) * 4;
#pragma unroll
    for (int i = 0; i < 4; i++)
#pragma unroll
        for (int j = 0; j < 4; j++) {
            size_t base = (size_t)(bm * 128 + wm + i * 16 + lro) * N + bn * 128 + wn + j * 16 + lr;
#pragma unroll
            for (int r = 0; r < 4; r++) C[base + (size_t)r * N] = (OUT_T)acc[i][j][r];
        }
}

// ---------------- merged projections: qkg (2048 blocks) + vt (1024 blocks) ----------------
__global__ __launch_bounds__(256) void gemm_proj(const __bf16* __restrict__ xb,
                                                 const __bf16* __restrict__ WT,
                                                 const __bf16* __restrict__ WvT,
                                                 __bf16* __restrict__ Cq,
                                                 __bf16* __restrict__ Cg,
                                                 __bf16* __restrict__ vt) {
    constexpr int K = 1024;
    __shared__ alignas(16) __bf16 As[2][4096];
    __shared__ alignas(16) __bf16 Bs[2][4096];
    const int tid = threadIdx.x;
    const int wv = tid >> 6;
    const int l = tid & 63;
    const int bid = blockIdx.x;
    const int wg = (bid & 7) * 384 + (bid >> 3);  // 3072 blocks, XCD swizzle
    const int mode = (wg >= 2048);
    int bm, bn;
    const __bf16 *Ab, *Bb;
    if (!mode) {
        bm = wg >> 5; bn = wg & 31;
        Ab = xb + (size_t)bm * 128 * K;
        Bb = WT + (size_t)bn * 128 * K;
    } else {
        const int w2 = wg - 2048;
        bm = w2 >> 6; bn = w2 & 63;
        Ab = WvT + (size_t)bm * 128 * K;
        Bb = xb + (size_t)bn * 128 * K;
    }
    const int L = (l << 4) ^ ((l >> 3) << 4);
    const int sr = L >> 6;
    const int sc8 = ((L >> 4) & 3) * 8;
    const int lr = tid & 15;
    const int ck = (tid >> 4) & 3;
    const int wm = (wv >> 1) * 64, wn = (wv & 1) * 64;

    auto STAGE = [&](int buf, int kt) {
        gload_lds16(Ab + (size_t)(wv * 16 + sr) * K + kt + sc8, &As[buf][0] + wv * 512);
        gload_lds16(Ab + (size_t)(64 + wv * 16 + sr) * K + kt + sc8, &As[buf][0] + 2048 + wv * 512);
        gload_lds16(Bb + (size_t)(wv * 16 + sr) * K + kt + sc8, &Bs[buf][0] + wv * 512);
        gload_lds16(Bb + (size_t)(64 + wv * 16 + sr) * K + kt + sc8, &Bs[buf][0] + 2048 + wv * 512);
    };

    const int nt = K >> 5;
    STAGE(0, 0);

    f32x4 acc[4][4] = {};
    for (int t = 0; t < nt; ++t) {
        __builtin_amdgcn_s_barrier();
        __builtin_amdgcn_sched_barrier(0);
        if (t + 1 < nt) {
            STAGE((t + 1) & 1, (t + 1) * 32);
            asm volatile("s_waitcnt vmcnt(4)" ::: "memory");
        } else {
            asm volatile("s_waitcnt vmcnt(0)" ::: "memory");
        }
        __builtin_amdgcn_sched_barrier(0);
        const __bf16* as = &As[t & 1][0];
        const __bf16* bs = &Bs[t & 1][0];
        bf16x8 af[4], bfr[4];
#pragma unroll
        for (int i = 0; i < 4; i++) af[i] = *(const bf16x8*)(as + lds_swz(wm + i * 16 + lr, ck));
#pragma unroll
        for (int j = 0; j < 4; j++) bfr[j] = *(const bf16x8*)(bs + lds_swz(wn + j * 16 + lr, ck));
#pragma unroll
        for (int i = 0; i < 4; i++)
#pragma unroll
            for (int j = 0; j < 4; j++) acc[i][j] = MFMA16(af[i], bfr[j], acc[i][j]);
        asm volatile("s_waitcnt lgkmcnt(0)" ::: "memory");
    }
    const int lro = ((tid >> 4) & 3) * 4;
    if (!mode) {
        __bf16* Cd = (bn < 16) ? Cq : Cg;
        const int col0 = (bn & 15) * 128;
#pragma unroll
        for (int i = 0; i < 4; i++)
#pragma unroll
            for (int j = 0; j < 4; j++) {
                size_t base = (size_t)(bm * 128 + wm + i * 16 + lro) * 2048 + col0 + wn + j * 16 + lr;
#pragma unroll
                for (int r = 0; r < 4; r++) Cd[base + (size_t)r * 2048] = (__bf16)acc[i][j][r];
            }
    } else {
#pragma unroll
        for (int i = 0; i < 4; i++)
#pragma unroll
            for (int j = 0; j < 4; j++) {
                size_t base = (size_t)(bm * 128 + wm + i * 16 + lro) * 8192 + bn * 128 + wn + j * 16 + lr;
#pragma unroll
                for (int r = 0; r < 4; r++) vt[base + (size_t)r * 8192] = (__bf16)acc[i][j][r];
            }
    }
}

// ---------------- per-(b,h,chunk128): gates, qg, kg, kgT, e^blast ----------------
__global__ __launch_bounds__(1024, 4) void gate_qkg(
    const float* __restrict__ tbuf, const float* __restrict__ w2,
    const float* __restrict__ b2, const __bf16* __restrict__ qkbuf,
    __bf16* __restrict__ qg, __bf16* __restrict__ kg,
    __bf16* __restrict__ kgT, float* __restrict__ ebl) {
    __shared__ alignas(16) float t_l[128 * 16];
    __shared__ float qs[4 * 256];
    __shared__ __bf16 kg_l[128 * 260];
    const int bid = blockIdx.x;
    const int bh = bid & 15, nc = bid >> 4;
    const int b = bh >> 2, h = bh & 3;
    const int tid = threadIdx.x;
    const int d = tid & 255, cq = tid >> 8;
    const int seq0 = b * 2048 + nc * 128;
    const int hd = h * 256 + d;

    for (int i = tid; i < 128 * 16; i += 1024) t_l[i] = tbuf[(size_t)seq0 * 16 + i];
    float w2c[16];
#pragma unroll
    for (int r = 0; r < 16; r++) w2c[r] = w2[r * 1024 + hd];
    const float b2v = b2[hd];
    __syncthreads();

    float bs[32];
    float run = 0.f;
#pragma unroll
    for (int j = 0; j < 32; j++) {
        const int c = cq * 32 + j;
        f32x4 t0 = *(const f32x4*)(t_l + c * 16);
        f32x4 t1 = *(const f32x4*)(t_l + c * 16 + 4);
        f32x4 t2 = *(const f32x4*)(t_l + c * 16 + 8);
        f32x4 t3 = *(const f32x4*)(t_l + c * 16 + 12);
        float u = b2v;
#pragma unroll
        for (int r = 0; r < 4; r++) {
            u = fmaf(t0[r], w2c[r], u);
            u = fmaf(t1[r], w2c[4 + r], u);
            u = fmaf(t2[r], w2c[8 + r], u);
            u = fmaf(t3[r], w2c[12 + r], u);
        }
        const float ls = fminf(u, 0.f) - __logf(1.f + __expf(-fabsf(u)));
        run += ls * 0.0625f;
        bs[j] = run;
    }
    qs[cq * 256 + d] = run;
    __syncthreads();

    float prefix = 0.f;
#pragma unroll
    for (int q = 0; q < 3; q++)
        if (q < cq) prefix += qs[q * 256 + d];

#pragma unroll
    for (int j = 0; j < 32; j++) {
        const int c = cq * 32 + j;
        const float bsum = prefix + bs[j];
        const float eb = __expf(bsum);
        const float en = __expf(-bsum);
        const float qv = (float)qkbuf[(size_t)(seq0 + c) * 2048 + hd];
        const float kv = (float)qkbuf[(size_t)(seq0 + c) * 2048 + 1024 + hd];
        qg[(size_t)(seq0 + c) * 1024 + hd] = (__bf16)(qv * eb * 0.0625f);
        const __bf16 kgv = (__bf16)(kv * en);
        kg[(size_t)(seq0 + c) * 1024 + hd] = kgv;
        kg_l[c * 260 + d] = kgv;
    }
    if (cq == 3) ebl[(size_t)(nc * 16 + bh) * 256 + d] = __expf(prefix + bs[31]);
    __syncthreads();

    {
        const int cc = tid & 127, dgroup = tid >> 7;
        for (int i = 0; i < 32; i++) {
            const int dd = dgroup * 32 + i;
            kgT[(size_t)(bh * 256 + dd) * 2048 + nc * 128 + cc] = kg_l[cc * 260 + dd];
        }
    }
}

// ---------------- merged: a_mat (blocks 0-255) + chunk_u (blocks 256-1279) ----------------
__global__ __launch_bounds__(512) void amat_chunku(
    const __bf16* __restrict__ qg, const __bf16* __restrict__ kg,
    __bf16* __restrict__ Abuf, const __bf16* __restrict__ vt,
    const __bf16* __restrict__ kgT, __bf16* __restrict__ UH) {
    const int tid = threadIdx.x, wv = tid >> 6, l = tid & 63;
    const int lr = l & 15, lk = (l >> 4) * 8, lro = (l >> 4) * 4;
    if (blockIdx.x < 256) {
        const int pair = blockIdx.x;
        const int bh = pair & 15, nc = pair >> 4;
        const int b = bh >> 2, h = bh & 3;
        const int seq0 = b * 2048 + nc * 128;
        __bf16* Ab = Abuf + (size_t)pair * 16384;
        {
            bf16x8 z = {};
            for (int i = tid; i < 2048; i += 512) *(bf16x8*)(Ab + (size_t)i * 8) = z;
        }
        __syncthreads();
        static const int TJ[36] = {0,1,1,2,2,2,3,3,3,3,4,4,4,4,4,5,5,5,5,5,5,
                                   6,6,6,6,6,6,6,7,7,7,7,7,7,7,7};
        static const int TS[36] = {0,0,1,0,1,2,0,1,2,3,0,1,2,3,4,0,1,2,3,4,5,
                                   0,1,2,3,4,5,6,0,1,2,3,4,5,6,7};
        for (int m = wv; m < 36; m += 8) {
            const int j = TJ[m], s = TS[m];
            f32x4 acc = {};
            const __bf16* qrow = qg + (size_t)(seq0 + j * 16 + lr) * 1024 + h * 256;
            const __bf16* krow = kg + (size_t)(seq0 + s * 16 + lr) * 1024 + h * 256;
#pragma unroll
            for (int ks = 0; ks < 8; ks++) {
                bf16x8 a = *(const bf16x8*)(qrow + ks * 32 + lk);
                bf16x8 bb = *(const bf16x8*)(krow + ks * 32 + lk);
                acc = MFMA16(a, bb, acc);
            }
#pragma unroll
            for (int r = 0; r < 4; r++) {
                const int t = j * 16 + lro + r;
                const int ss = s * 16 + lr;
                if (ss <= t) Ab[t * 128 + ss] = (__bf16)acc[r];
            }
        }
    } else {
        const int bid = blockIdx.x - 256;
        const int bh = bid & 15, nc = (bid >> 4) & 15, q = bid >> 8;
        const int eh = q >> 1, dh = q & 1;
        const int b = bh >> 2, h = bh & 3;
        const int seq0 = b * 2048 + nc * 128;
        const int e0 = eh * 256 + (wv >> 1) * 64;
        const int d0 = dh * 128 + (wv & 1) * 64;
        const __bf16* va = vt + (size_t)(h * 512 + e0) * 8192 + seq0;
        const __bf16* kb = kgT + (size_t)(bh * 256 + d0) * 2048 + nc * 128;

        f32x4 acc[4][4] = {};
#pragma unroll
        for (int ks = 0; ks < 4; ks++) {
            bf16x8 af[4], bf_[4];
#pragma unroll
            for (int i = 0; i < 4; i++)
                af[i] = *(const bf16x8*)(va + (size_t)(i * 16 + lr) * 8192 + ks * 32 + lk);
#pragma unroll
            for (int j = 0; j < 4; j++)
                bf_[j] = *(const bf16x8*)(kb + (size_t)(j * 16 + lr) * 2048 + ks * 32 + lk);
#pragma unroll
            for (int i = 0; i < 4; i++)
#pragma unroll
                for (int j = 0; j < 4; j++) acc[i][j] = MFMA16(af[i], bf_[j], acc[i][j]);
        }
        __bf16* ub = UH + ((size_t)(nc * 16 + bh) * 512 + e0) * 256 + d0;
#pragma unroll
        for (int i = 0; i < 4; i++)
#pragma unroll
            for (int j = 0; j < 4; j++)
#pragma unroll
                for (int r = 0; r < 4; r++)
                    ub[(size_t)(i * 16 + lro + r) * 256 + j * 16 + lr] = (__bf16)acc[i][j][r];
    }
}

// ---------------- ointer: o = [A|qg] @ [vt_slice | H_slot]^T (r12 pipeline) ----------------
__global__ __launch_bounds__(256) void ointer(
    const __bf16* __restrict__ Abuf, const __bf16* __restrict__ qg,
    const __bf16* __restrict__ vt, const __bf16* __restrict__ UH,
    __bf16* __restrict__ ob) {
    __shared__ alignas(16) __bf16 As[2][4096];
    __shared__ alignas(16) __bf16 Bs[2][4096];
    const int tid = threadIdx.x;
    const int wv = tid >> 6;
    const int l = tid & 63;
    const int bid = blockIdx.x;
    const int wg = (bid & 7) * 128 + (bid >> 3);
    const int bn = wg & 3, pair = wg >> 2;
    const int bh = pair & 15, nc = pair >> 4;
    const int b = bh >> 2, h = bh & 3;
    const int seq0 = b * 2048 + nc * 128;
    const int L = (l << 4) ^ ((l >> 3) << 4);
    const int sr = L >> 6;
    const int sc8 = ((L >> 4) & 3) * 8;
    const int lr = tid & 15;
    const int ck = (tid >> 4) & 3;
    const int wm = (wv >> 1) * 64, wn = (wv & 1) * 64;
    const int KE = (nc == 0) ? 128 : 384;

    const __bf16* Ap = Abuf + (size_t)pair * 16384;
    const __bf16* Hb = UH + ((size_t)((nc - 1) * 16 + bh) * 512 + bn * 128) * 256;

    auto STAGE = [&](int buf, int kt) {
        const __bf16 *a0, *a1, *b0, *b1;
        if (kt < 128) {
            a0 = Ap + (size_t)(wv * 16 + sr) * 128 + kt + sc8;
            a1 = Ap + (size_t)(64 + wv * 16 + sr) * 128 + kt + sc8;
            b0 = vt + (size_t)(h * 512 + bn * 128 + wv * 16 + sr) * 8192 + seq0 + kt + sc8;
            b1 = vt + (size_t)(h * 512 + bn * 128 + 64 + wv * 16 + sr) * 8192 + seq0 + kt + sc8;
        } else {
            const int kd = kt - 128;
            a0 = qg + (size_t)(seq0 + wv * 16 + sr) * 1024 + h * 256 + kd + sc8;
            a1 = qg + (size_t)(seq0 + 64 + wv * 16 + sr) * 1024 + h * 256 + kd + sc8;
            b0 = Hb + (size_t)(wv * 16 + sr) * 256 + kd + sc8;
            b1 = Hb + (size_t)(64 + wv * 16 + sr) * 256 + kd + sc8;
        }
        gload_lds16(a0, &As[buf][0] + wv * 512);
        gload_lds16(a1, &As[buf][0] + 2048 + wv * 512);
        gload_lds16(b0, &Bs[buf][0] + wv * 512);
        gload_lds16(b1, &Bs[buf][0] + 2048 + wv * 512);
    };

    const int nt = KE >> 5;
    STAGE(0, 0);

    f32x4 acc[4][4] = {};
    for (int t = 0; t < nt; ++t) {
        __builtin_amdgcn_s_barrier();
        __builtin_amdgcn_sched_barrier(0);
        if (t + 1 < nt) {
            STAGE((t + 1) & 1, (t + 1) * 32);
            asm volatile("s_waitcnt vmcnt(4)" ::: "memory");
        } else {
            asm volatile("s_waitcnt vmcnt(0)" ::: "memory");
        }
        __builtin_amdgcn_sched_barrier(0);
        const __bf16* as = &As[t & 1][0];
        const __bf16* bs = &Bs[t & 1][0];
        bf16x8 af[4], bfr[4];
#pragma unroll
        for (int i = 0; i < 4; i++) af[i] = *(const bf16x8*)(as + lds_swz(wm + i * 16 + lr, ck));
#pragma unroll
        for (int j = 0; j < 4; j++) bfr[j] = *(const bf16x8*)(bs + lds_swz(wn + j * 16 + lr, ck));
#pragma unroll
        for (int i = 0; i < 4; i++)
#pragma unroll
            for (int j = 0; j < 4; j++) acc[i][j] = MFMA16(af[i], bfr[j], acc[i][j]);
        asm volatile("s_waitcnt lgkmcnt(0)" ::: "memory");
    }
    const int lro = ((tid >> 4) & 3) * 4;
#pragma unroll
    for (int i = 0; i < 4; i++)
#pragma unroll
        for (int j = 0; j < 4; j++) {
            size_t base = (size_t)(seq0 + wm + i * 16 + lro) * 2048 + h * 512 + bn * 128 + wn + j * 16 + lr;
#pragma unroll
            for (int r = 0; r < 4; r++) ob[base + (size_t)r * 2048] = (__bf16)acc[i][j][r];
        }
}

// ---------------- hscan: in-place elementwise scan over 16 chunk slots ----------------
__global__ __launch_bounds__(256) void hscan(__bf16* __restrict__ UH,
                                             const float* __restrict__ ebl) {
    const int t = blockIdx.x * 256 + threadIdx.x;
    const int bh = t >> 14;
    const int rem = t & 16383;
    const int e = rem >> 5, d0 = (rem & 31) * 8;
    float H[8];
#pragma unroll
    for (int j = 0; j < 8; j++) H[j] = 0.f;
    for (int i = 0; i < 16; i++) {
        size_t idx = ((size_t)(i * 16 + bh) * 512 + e) * 256 + d0;
        bf16x8 u = *(const bf16x8*)(UH + idx);
        const float* ep = ebl + (size_t)(i * 16 + bh) * 256 + d0;
        f32x4 e0v = *(const f32x4*)ep;
        f32x4 e1v = *(const f32x4*)(ep + 4);
        bf16x8 hw;
#pragma unroll
        for (int j = 0; j < 4; j++) {
            H[j] = e0v[j] * (H[j] + (float)u[j]);
            hw[j] = (__bf16)H[j];
        }
#pragma unroll
        for (int j = 4; j < 8; j++) {
            H[j] = e1v[j - 4] * (H[j] + (float)u[j]);
            hw[j] = (__bf16)H[j];
        }
        *(bf16x8*)(UH + idx) = hw;
    }
}

// ---------------- RMS norm over dv=512 + SiLU gating ----------------
__global__ __launch_bounds__(256) void rms_gate(const __bf16* __restrict__ ob,
                                                const __bf16* __restrict__ gbuf,
                                                const float* __restrict__ gnw,
                                                __bf16* __restrict__ gated) {
    const int idx = blockIdx.x * 4 + (threadIdx.x >> 6);
    const int seq = idx >> 2, h = idx & 3;
    const int l = threadIdx.x & 63;
    bf16x8 o1 = *(const bf16x8*)(ob + (size_t)seq * 2048 + h * 512 + l * 8);
    float v[8];
    float ms = 0.f;
#pragma unroll
    for (int j = 0; j < 8; j++) {
        v[j] = (float)o1[j];
        ms += v[j] * v[j];
    }
#pragma unroll
    for (int off = 1; off < 64; off <<= 1) ms += __shfl_xor(ms, off);
    const float rinv = rsqrtf(ms * (1.f / 512.f) + 1e-5f);
    bf16x8 gv = *(const bf16x8*)(gbuf + (size_t)seq * 2048 + h * 512 + l * 8);
    const float* gw = gnw + l * 8;
    bf16x8 outv;
#pragma unroll
    for (int j = 0; j < 8; j++) {
        float g = (float)gv[j];
        float sig = 1.f / (1.f + expf(-g));
        outv[j] = (__bf16)(v[j] * rinv * gw[j] * g * sig);
    }
    *(bf16x8*)(gated + (size_t)seq * 2048 + h * 512 + l * 8) = outv;
}

extern "C" void kernel_launch(void* const* d_in, const int* in_sizes, int n_in,
                              void* d_out, int out_size, void* d_ws, size_t ws_size,
                              hipStream_t stream) {
    const float* x = (const float*)d_in[0];
    const float* Wq = (const float*)d_in[1];
    const float* Wk = (const float*)d_in[2];
    const float* Wv = (const float*)d_in[3];
    const float* Wg = (const float*)d_in[4];
    const float* w1 = (const float*)d_in[5];
    const float* w2 = (const float*)d_in[6];
    const float* b2 = (const float*)d_in[7];
    const float* gnw = (const float*)d_in[8];
    const float* Wo = (const float*)d_in[9];
    float* out = (float*)d_out;

    char* p = (char*)d_ws;
    auto nxt = [&](size_t bytes) {
        char* r = p;
        p += (bytes + 255) & ~(size_t)255;
        return r;
    };
    __bf16* xb = (__bf16*)nxt(8192ull * 1024 * 2);
    __bf16* WTqk = (__bf16*)nxt(2048ull * 1024 * 2);
    __bf16* WTg = (__bf16*)nxt(2048ull * 1024 * 2);
    __bf16* WvT = (__bf16*)nxt(2048ull * 1024 * 2);
    __bf16* WoT = (__bf16*)nxt(1024ull * 2048 * 2);
    __bf16* gbuf = (__bf16*)nxt(8192ull * 2048 * 2);
    __bf16* vt = (__bf16*)nxt(2048ull * 8192 * 2);
    float* tbuf = (float*)nxt(8192ull * 16 * 4);
    __bf16* qg = (__bf16*)nxt(8192ull * 1024 * 2);
    __bf16* kgT = (__bf16*)nxt(16ull * 256 * 2048 * 2);
    float* ebl = (float*)nxt(16ull * 16 * 256 * 4);
    __bf16* ob = (__bf16*)nxt(8192ull * 2048 * 2);
    __bf16* UH = (__bf16*)nxt(16ull * 16 * 512 * 256 * 2);
    __bf16* kg = xb;        // alias: xb dead before gate_qkg writes kg
    __bf16* qkbuf = UH;     // alias: dead before amat_chunku writes UH
    __bf16* gated = UH;     // alias: UH dead (read by ointer) before rms_gate writes gated
    __bf16* Abuf = WTqk;    // alias: 8MB = WTqk+WTg, both dead before amat_chunku

    prep<<<10240, 256, 0, stream>>>(x, w1, tbuf, xb, Wq, Wk, Wg, Wv, Wo, WTqk, WTg, WvT, WoT);
    gemm_proj<<<3072, 256, 0, stream>>>(xb, WTqk, WvT, qkbuf, gbuf, vt);
    gate_qkg<<<256, 1024, 0, stream>>>(tbuf, w2, b2, qkbuf, qg, kg, kgT, ebl);
    amat_chunku<<<1280, 512, 0, stream>>>(qg, kg, Abuf, vt, kgT, UH);
    hscan<<<1024, 256, 0, stream>>>(UH, ebl);
    ointer<<<1024, 256, 0, stream>>>(Abuf, qg, vt, UH, ob);
    rms_gate<<<8192, 256, 0, stream>>>(ob, gbuf, gnw, gated);
    gemm_bt<float><<<512, 256, 0, stream>>>(gated, WoT, out, 8192, 1024, 2048);
}

// Round 20
// 371.214 us; speedup vs baseline: 1.1169x; 1.0054x over previous
//
#include <hip/hip_runtime.h>
#include <hip/hip_bf16.h>

typedef __attribute__((ext_vector_type(8))) __bf16 bf16x8;
typedef __attribute__((ext_vector_type(4))) __bf16 bf16x4;
typedef __attribute__((ext_vector_type(4))) float f32x4;

#define MFMA16(a, b, c) __builtin_amdgcn_mfma_f32_16x16x32_bf16((a), (b), (c), 0, 0, 0)

__device__ __forceinline__ void gload_lds16(const void* g, void* l) {
    __builtin_amdgcn_global_load_lds((const __attribute__((address_space(1))) void*)g,
                                     (__attribute__((address_space(3))) void*)l, 16, 0, 0);
}

// XOR-swizzle within each 1KB (16-row) region of a [R][32]bf16 LDS tile (64B rows).
// Measured (r10): SQ_LDS_BANK_CONFLICT 4.2M -> 0.
__device__ __forceinline__ int lds_swz(int r, int ck) {
    int W = ((r & 15) << 6) | (ck << 4);
    W ^= ((W >> 7) & 7) << 4;
    return ((r >> 4) << 9) + (W >> 1);
}

// ---------------- prep: gk1+cvt (blocks 0-2047) and 5 weight transposes (2048-10239) ----------
__global__ __launch_bounds__(256) void prep(
    const float* __restrict__ x, const float* __restrict__ w1,
    float* __restrict__ t, __bf16* __restrict__ xb,
    const float* __restrict__ Wq, const float* __restrict__ Wk,
    const float* __restrict__ Wg, const float* __restrict__ Wv,
    const float* __restrict__ Wo, __bf16* __restrict__ WTqk,
    __bf16* __restrict__ WTg, __bf16* __restrict__ WvT, __bf16* __restrict__ WoT) {
    __shared__ float tile[32][33];
    if (blockIdx.x < 2048) {
        const int row = blockIdx.x * 4 + (threadIdx.x >> 6);
        const int l = threadIdx.x & 63;
        const int r = l & 15, kg = l >> 4;
        const float* xr = x + (size_t)row * 1024;
        const float* w1p = w1 + r;
        float acc = 0.f;
        for (int k = kg * 256; k < (kg + 1) * 256; ++k) acc = fmaf(xr[k], w1p[k * 16], acc);
        acc += __shfl_xor(acc, 16);
        acc += __shfl_xor(acc, 32);
        if (kg == 0) t[(size_t)row * 16 + r] = acc;

        const size_t base = (size_t)blockIdx.x * 4096 + threadIdx.x * 16;
#pragma unroll
        for (int v = 0; v < 4; v++) {
            f32x4 f = *(const f32x4*)(x + base + v * 4);
            bf16x4 o;
#pragma unroll
            for (int j = 0; j < 4; j++) o[j] = (__bf16)f[j];
            *(bf16x4*)(xb + base + v * 4) = o;
        }
        return;
    }
    const int bid = blockIdx.x - 2048;
    const float* in;
    __bf16* out;
    int R, C, loc, gw;
    if (bid < 1024)      { in = Wq; out = WTqk;            R = 1024; C = 1024; loc = bid;        gw = 32; }
    else if (bid < 2048) { in = Wk; out = WTqk + 1048576;  R = 1024; C = 1024; loc = bid - 1024; gw = 32; }
    else if (bid < 4096) { in = Wg; out = WTg;             R = 1024; C = 2048; loc = bid - 2048; gw = 64; }
    else if (bid < 6144) { in = Wv; out = WvT;             R = 1024; C = 2048; loc = bid - 4096; gw = 64; }
    else                 { in = Wo; out = WoT;             R = 2048; C = 1024; loc = bid - 6144; gw = 32; }
    const int c0 = (loc % gw) * 32, r0 = (loc / gw) * 32;
    const int tx = threadIdx.x & 31, ty = threadIdx.x >> 5;
#pragma unroll
    for (int k = 0; k < 32; k += 8)
        tile[ty + k][tx] = in[(size_t)(r0 + ty + k) * C + c0 + tx];
    __syncthreads();
#pragma unroll
    for (int k = 0; k < 32; k += 8)
        out[(size_t)(c0 + ty + k) * R + r0 + tx] = (__bf16)tile[tx][ty + k];
}

// ---------------- GEMM: C(M,N) = A(M,K)bf16 @ Bt(N,K)bf16^T (r12 pipeline) ----------------
template <typename OUT_T>
__global__ __launch_bounds__(256) void gemm_bt(const __bf16* __restrict__ A,
                                               const __bf16* __restrict__ Bt,
                                               OUT_T* __restrict__ C, int M, int N, int K) {
    __shared__ alignas(16) __bf16 As[2][4096];
    __shared__ alignas(16) __bf16 Bs[2][4096];
    const int tid = threadIdx.x;
    const int wv = tid >> 6;
    const int l = tid & 63;
    const int nwg = gridDim.x;
    const int cpx = nwg >> 3;
    const int bid = blockIdx.x;
    const int wg = (bid & 7) * cpx + (bid >> 3);
    const int nbn = N >> 7;
    const int bm = wg / nbn, bn = wg - bm * nbn;

    const __bf16* Ab = A + (size_t)bm * 128 * K;
    const __bf16* Bb = Bt + (size_t)bn * 128 * K;
    const int L = (l << 4) ^ ((l >> 3) << 4);
    const int sr = L >> 6;
    const int sc8 = ((L >> 4) & 3) * 8;
    const int lr = tid & 15;
    const int ck = (tid >> 4) & 3;
    const int wm = (wv >> 1) * 64, wn = (wv & 1) * 64;

    auto STAGE = [&](int buf, int kt) {
        gload_lds16(Ab + (size_t)(wv * 16 + sr) * K + kt + sc8, &As[buf][0] + wv * 512);
        gload_lds16(Ab + (size_t)(64 + wv * 16 + sr) * K + kt + sc8, &As[buf][0] + 2048 + wv * 512);
        gload_lds16(Bb + (size_t)(wv * 16 + sr) * K + kt + sc8, &Bs[buf][0] + wv * 512);
        gload_lds16(Bb + (size_t)(64 + wv * 16 + sr) * K + kt + sc8, &Bs[buf][0] + 2048 + wv * 512);
    };

    const int nt = K >> 5;
    STAGE(0, 0);

    f32x4 acc[4][4] = {};
    for (int t = 0; t < nt; ++t) {
        __builtin_amdgcn_s_barrier();
        __builtin_amdgcn_sched_barrier(0);
        if (t + 1 < nt) {
            STAGE((t + 1) & 1, (t + 1) * 32);
            asm volatile("s_waitcnt vmcnt(4)" ::: "memory");
        } else {
            asm volatile("s_waitcnt vmcnt(0)" ::: "memory");
        }
        __builtin_amdgcn_sched_barrier(0);
        const __bf16* as = &As[t & 1][0];
        const __bf16* bs = &Bs[t & 1][0];
        bf16x8 af[4], bfr[4];
#pragma unroll
        for (int i = 0; i < 4; i++) af[i] = *(const bf16x8*)(as + lds_swz(wm + i * 16 + lr, ck));
#pragma unroll
        for (int j = 0; j < 4; j++) bfr[j] = *(const bf16x8*)(bs + lds_swz(wn + j * 16 + lr, ck));
#pragma unroll
        for (int i = 0; i < 4; i++)
#pragma unroll
            for (int j = 0; j < 4; j++) acc[i][j] = MFMA16(af[i], bfr[j], acc[i][j]);
        asm volatile("s_waitcnt lgkmcnt(0)" ::: "memory");
    }
    const int lro = ((tid >> 4) & 3) * 4;
#pragma unroll
    for (int i = 0; i < 4; i++)
#pragma unroll
        for (int j = 0; j < 4; j++) {
            size_t base = (size_t)(bm * 128 + wm + i * 16 + lro) * N + bn * 128 + wn + j * 16 + lr;
#pragma unroll
            for (int r = 0; r < 4; r++) C[base + (size_t)r * N] = (OUT_T)acc[i][j][r];
        }
}

// ---------------- merged projections: qkg (2048 blocks) + vt (1024 blocks) ----------------
__global__ __launch_bounds__(256) void gemm_proj(const __bf16* __restrict__ xb,
                                                 const __bf16* __restrict__ WT,
                                                 const __bf16* __restrict__ WvT,
                                                 __bf16* __restrict__ Cq,
                                                 __bf16* __restrict__ Cg,
                                                 __bf16* __restrict__ vt) {
    constexpr int K = 1024;
    __shared__ alignas(16) __bf16 As[2][4096];
    __shared__ alignas(16) __bf16 Bs[2][4096];
    const int tid = threadIdx.x;
    const int wv = tid >> 6;
    const int l = tid & 63;
    const int bid = blockIdx.x;
    const int wg = (bid & 7) * 384 + (bid >> 3);  // 3072 blocks, XCD swizzle
    const int mode = (wg >= 2048);
    int bm, bn;
    const __bf16 *Ab, *Bb;
    if (!mode) {
        bm = wg >> 5; bn = wg & 31;
        Ab = xb + (size_t)bm * 128 * K;
        Bb = WT + (size_t)bn * 128 * K;
    } else {
        const int w2 = wg - 2048;
        bm = w2 >> 6; bn = w2 & 63;
        Ab = WvT + (size_t)bm * 128 * K;
        Bb = xb + (size_t)bn * 128 * K;
    }
    const int L = (l << 4) ^ ((l >> 3) << 4);
    const int sr = L >> 6;
    const int sc8 = ((L >> 4) & 3) * 8;
    const int lr = tid & 15;
    const int ck = (tid >> 4) & 3;
    const int wm = (wv >> 1) * 64, wn = (wv & 1) * 64;

    auto STAGE = [&](int buf, int kt) {
        gload_lds16(Ab + (size_t)(wv * 16 + sr) * K + kt + sc8, &As[buf][0] + wv * 512);
        gload_lds16(Ab + (size_t)(64 + wv * 16 + sr) * K + kt + sc8, &As[buf][0] + 2048 + wv * 512);
        gload_lds16(Bb + (size_t)(wv * 16 + sr) * K + kt + sc8, &Bs[buf][0] + wv * 512);
        gload_lds16(Bb + (size_t)(64 + wv * 16 + sr) * K + kt + sc8, &Bs[buf][0] + 2048 + wv * 512);
    };

    const int nt = K >> 5;
    STAGE(0, 0);

    f32x4 acc[4][4] = {};
    for (int t = 0; t < nt; ++t) {
        __builtin_amdgcn_s_barrier();
        __builtin_amdgcn_sched_barrier(0);
        if (t + 1 < nt) {
            STAGE((t + 1) & 1, (t + 1) * 32);
            asm volatile("s_waitcnt vmcnt(4)" ::: "memory");
        } else {
            asm volatile("s_waitcnt vmcnt(0)" ::: "memory");
        }
        __builtin_amdgcn_sched_barrier(0);
        const __bf16* as = &As[t & 1][0];
        const __bf16* bs = &Bs[t & 1][0];
        bf16x8 af[4], bfr[4];
#pragma unroll
        for (int i = 0; i < 4; i++) af[i] = *(const bf16x8*)(as + lds_swz(wm + i * 16 + lr, ck));
#pragma unroll
        for (int j = 0; j < 4; j++) bfr[j] = *(const bf16x8*)(bs + lds_swz(wn + j * 16 + lr, ck));
#pragma unroll
        for (int i = 0; i < 4; i++)
#pragma unroll
            for (int j = 0; j < 4; j++) acc[i][j] = MFMA16(af[i], bfr[j], acc[i][j]);
        asm volatile("s_waitcnt lgkmcnt(0)" ::: "memory");
    }
    const int lro = ((tid >> 4) & 3) * 4;
    if (!mode) {
        __bf16* Cd = (bn < 16) ? Cq : Cg;
        const int col0 = (bn & 15) * 128;
#pragma unroll
        for (int i = 0; i < 4; i++)
#pragma unroll
            for (int j = 0; j < 4; j++) {
                size_t base = (size_t)(bm * 128 + wm + i * 16 + lro) * 2048 + col0 + wn + j * 16 + lr;
#pragma unroll
                for (int r = 0; r < 4; r++) Cd[base + (size_t)r * 2048] = (__bf16)acc[i][j][r];
            }
    } else {
#pragma unroll
        for (int i = 0; i < 4; i++)
#pragma unroll
            for (int j = 0; j < 4; j++) {
                size_t base = (size_t)(bm * 128 + wm + i * 16 + lro) * 8192 + bn * 128 + wn + j * 16 + lr;
#pragma unroll
                for (int r = 0; r < 4; r++) vt[base + (size_t)r * 8192] = (__bf16)acc[i][j][r];
            }
    }
}

// ---------------- per-(b,h,chunk128,d-half): gates, qg, kg, kgT, e^blast ----------------
// grid 512 = dh(2) x nc(16) x bh(16); block 1024 = 8 c-octants x 128 d.
// Serial chain 16 (was 32); octant prefix via LDS. d-columns independent -> exact split.
__global__ __launch_bounds__(1024, 2) void gate_qkg(
    const float* __restrict__ tbuf, const float* __restrict__ w2,
    const float* __restrict__ b2, const __bf16* __restrict__ qkbuf,
    __bf16* __restrict__ qg, __bf16* __restrict__ kg,
    __bf16* __restrict__ kgT, float* __restrict__ ebl) {
    __shared__ alignas(16) float t_l[128 * 16];  // 8KB
    __shared__ float qs[8 * 128];                // 4KB octant totals
    __shared__ __bf16 kg_l[128 * 132];           // 33.8KB (this d-half)
    const int bid = blockIdx.x;
    const int bh = bid & 15, nc = (bid >> 4) & 15, dh = bid >> 8;
    const int b = bh >> 2, h = bh & 3;
    const int tid = threadIdx.x;
    const int dl = tid & 127, cq = tid >> 7;  // d-local, c-octant
    const int d = dh * 128 + dl;
    const int seq0 = b * 2048 + nc * 128;
    const int hd = h * 256 + d;

    for (int i = tid; i < 128 * 16; i += 1024) t_l[i] = tbuf[(size_t)seq0 * 16 + i];
    float w2c[16];
#pragma unroll
    for (int r = 0; r < 16; r++) w2c[r] = w2[r * 1024 + hd];
    const float b2v = b2[hd];
    __syncthreads();

    // phase B: within-octant inclusive cumsum (16 steps, registers)
    float bs[16];
    float run = 0.f;
#pragma unroll
    for (int j = 0; j < 16; j++) {
        const int c = cq * 16 + j;
        f32x4 t0 = *(const f32x4*)(t_l + c * 16);
        f32x4 t1 = *(const f32x4*)(t_l + c * 16 + 4);
        f32x4 t2 = *(const f32x4*)(t_l + c * 16 + 8);
        f32x4 t3 = *(const f32x4*)(t_l + c * 16 + 12);
        float u = b2v;
#pragma unroll
        for (int r = 0; r < 4; r++) {
            u = fmaf(t0[r], w2c[r], u);
            u = fmaf(t1[r], w2c[4 + r], u);
            u = fmaf(t2[r], w2c[8 + r], u);
            u = fmaf(t3[r], w2c[12 + r], u);
        }
        const float ls = fminf(u, 0.f) - __logf(1.f + __expf(-fabsf(u)));
        run += ls * 0.0625f;
        bs[j] = run;
    }
    qs[cq * 128 + dl] = run;
    __syncthreads();

    float prefix = 0.f;
#pragma unroll
    for (int q = 0; q < 7; q++)
        if (q < cq) prefix += qs[q * 128 + dl];

    // phase C: apply gates to q/k (16 c's per thread)
#pragma unroll
    for (int j = 0; j < 16; j++) {
        const int c = cq * 16 + j;
        const float bsum = prefix + bs[j];
        const float eb = __expf(bsum);
        const float en = __expf(-bsum);
        const float qv = (float)qkbuf[(size_t)(seq0 + c) * 2048 + hd];
        const float kv = (float)qkbuf[(size_t)(seq0 + c) * 2048 + 1024 + hd];
        qg[(size_t)(seq0 + c) * 1024 + hd] = (__bf16)(qv * eb * 0.0625f);
        const __bf16 kgv = (__bf16)(kv * en);
        kg[(size_t)(seq0 + c) * 1024 + hd] = kgv;
        kg_l[c * 132 + dl] = kgv;
    }
    if (cq == 7) ebl[(size_t)(nc * 16 + bh) * 256 + d] = __expf(prefix + bs[15]);
    __syncthreads();

    // phase D: transpose this d-half of kg -> kgT
    {
        const int cc = tid & 127, dgroup = tid >> 7;  // 8 groups of 16 d-locals
        for (int i = 0; i < 16; i++) {
            const int ddl = dgroup * 16 + i;
            kgT[(size_t)(bh * 256 + dh * 128 + ddl) * 2048 + nc * 128 + cc] = kg_l[cc * 132 + ddl];
        }
    }
}

// ---------------- merged: a_mat (blocks 0-255) + chunk_u (blocks 256-1279) ----------------
__global__ __launch_bounds__(512) void amat_chunku(
    const __bf16* __restrict__ qg, const __bf16* __restrict__ kg,
    __bf16* __restrict__ Abuf, const __bf16* __restrict__ vt,
    const __bf16* __restrict__ kgT, __bf16* __restrict__ UH) {
    const int tid = threadIdx.x, wv = tid >> 6, l = tid & 63;
    const int lr = l & 15, lk = (l >> 4) * 8, lro = (l >> 4) * 4;
    if (blockIdx.x < 256) {
        const int pair = blockIdx.x;
        const int bh = pair & 15, nc = pair >> 4;
        const int b = bh >> 2, h = bh & 3;
        const int seq0 = b * 2048 + nc * 128;
        __bf16* Ab = Abuf + (size_t)pair * 16384;
        {
            bf16x8 z = {};
            for (int i = tid; i < 2048; i += 512) *(bf16x8*)(Ab + (size_t)i * 8) = z;
        }
        __syncthreads();
        static const int TJ[36] = {0,1,1,2,2,2,3,3,3,3,4,4,4,4,4,5,5,5,5,5,5,
                                   6,6,6,6,6,6,6,7,7,7,7,7,7,7,7};
        static const int TS[36] = {0,0,1,0,1,2,0,1,2,3,0,1,2,3,4,0,1,2,3,4,5,
                                   0,1,2,3,4,5,6,0,1,2,3,4,5,6,7};
        for (int m = wv; m < 36; m += 8) {
            const int j = TJ[m], s = TS[m];
            f32x4 acc = {};
            const __bf16* qrow = qg + (size_t)(seq0 + j * 16 + lr) * 1024 + h * 256;
            const __bf16* krow = kg + (size_t)(seq0 + s * 16 + lr) * 1024 + h * 256;
#pragma unroll
            for (int ks = 0; ks < 8; ks++) {
                bf16x8 a = *(const bf16x8*)(qrow + ks * 32 + lk);
                bf16x8 bb = *(const bf16x8*)(krow + ks * 32 + lk);
                acc = MFMA16(a, bb, acc);
            }
#pragma unroll
            for (int r = 0; r < 4; r++) {
                const int t = j * 16 + lro + r;
                const int ss = s * 16 + lr;
                if (ss <= t) Ab[t * 128 + ss] = (__bf16)acc[r];
            }
        }
    } else {
        const int bid = blockIdx.x - 256;
        const int bh = bid & 15, nc = (bid >> 4) & 15, q = bid >> 8;
        const int eh = q >> 1, dh = q & 1;
        const int b = bh >> 2, h = bh & 3;
        const int seq0 = b * 2048 + nc * 128;
        const int e0 = eh * 256 + (wv >> 1) * 64;
        const int d0 = dh * 128 + (wv & 1) * 64;
        const __bf16* va = vt + (size_t)(h * 512 + e0) * 8192 + seq0;
        const __bf16* kb = kgT + (size_t)(bh * 256 + d0) * 2048 + nc * 128;

        f32x4 acc[4][4] = {};
#pragma unroll
        for (int ks = 0; ks < 4; ks++) {
            bf16x8 af[4], bf_[4];
#pragma unroll
            for (int i = 0; i < 4; i++)
                af[i] = *(const bf16x8*)(va + (size_t)(i * 16 + lr) * 8192 + ks * 32 + lk);
#pragma unroll
            for (int j = 0; j < 4; j++)
                bf_[j] = *(const bf16x8*)(kb + (size_t)(j * 16 + lr) * 2048 + ks * 32 + lk);
#pragma unroll
            for (int i = 0; i < 4; i++)
#pragma unroll
                for (int j = 0; j < 4; j++) acc[i][j] = MFMA16(af[i], bf_[j], acc[i][j]);
        }
        __bf16* ub = UH + ((size_t)(nc * 16 + bh) * 512 + e0) * 256 + d0;
#pragma unroll
        for (int i = 0; i < 4; i++)
#pragma unroll
            for (int j = 0; j < 4; j++)
#pragma unroll
                for (int r = 0; r < 4; r++)
                    ub[(size_t)(i * 16 + lro + r) * 256 + j * 16 + lr] = (__bf16)acc[i][j][r];
    }
}

// ---------------- ointer: o = [A|qg] @ [vt_slice | H_slot]^T (r12 pipeline) ----------------
__global__ __launch_bounds__(256) void ointer(
    const __bf16* __restrict__ Abuf, const __bf16* __restrict__ qg,
    const __bf16* __restrict__ vt, const __bf16* __restrict__ UH,
    __bf16* __restrict__ ob) {
    __shared__ alignas(16) __bf16 As[2][4096];
    __shared__ alignas(16) __bf16 Bs[2][4096];
    const int tid = threadIdx.x;
    const int wv = tid >> 6;
    const int l = tid & 63;
    const int bid = blockIdx.x;
    const int wg = (bid & 7) * 128 + (bid >> 3);
    const int bn = wg & 3, pair = wg >> 2;
    const int bh = pair & 15, nc = pair >> 4;
    const int b = bh >> 2, h = bh & 3;
    const int seq0 = b * 2048 + nc * 128;
    const int L = (l << 4) ^ ((l >> 3) << 4);
    const int sr = L >> 6;
    const int sc8 = ((L >> 4) & 3) * 8;
    const int lr = tid & 15;
    const int ck = (tid >> 4) & 3;
    const int wm = (wv >> 1) * 64, wn = (wv & 1) * 64;
    const int KE = (nc == 0) ? 128 : 384;

    const __bf16* Ap = Abuf + (size_t)pair * 16384;
    const __bf16* Hb = UH + ((size_t)((nc - 1) * 16 + bh) * 512 + bn * 128) * 256;

    auto STAGE = [&](int buf, int kt) {
        const __bf16 *a0, *a1, *b0, *b1;
        if (kt < 128) {
            a0 = Ap + (size_t)(wv * 16 + sr) * 128 + kt + sc8;
            a1 = Ap + (size_t)(64 + wv * 16 + sr) * 128 + kt + sc8;
            b0 = vt + (size_t)(h * 512 + bn * 128 + wv * 16 + sr) * 8192 + seq0 + kt + sc8;
            b1 = vt + (size_t)(h * 512 + bn * 128 + 64 + wv * 16 + sr) * 8192 + seq0 + kt + sc8;
        } else {
            const int kd = kt - 128;
            a0 = qg + (size_t)(seq0 + wv * 16 + sr) * 1024 + h * 256 + kd + sc8;
            a1 = qg + (size_t)(seq0 + 64 + wv * 16 + sr) * 1024 + h * 256 + kd + sc8;
            b0 = Hb + (size_t)(wv * 16 + sr) * 256 + kd + sc8;
            b1 = Hb + (size_t)(64 + wv * 16 + sr) * 256 + kd + sc8;
        }
        gload_lds16(a0, &As[buf][0] + wv * 512);
        gload_lds16(a1, &As[buf][0] + 2048 + wv * 512);
        gload_lds16(b0, &Bs[buf][0] + wv * 512);
        gload_lds16(b1, &Bs[buf][0] + 2048 + wv * 512);
    };

    const int nt = KE >> 5;
    STAGE(0, 0);

    f32x4 acc[4][4] = {};
    for (int t = 0; t < nt; ++t) {
        __builtin_amdgcn_s_barrier();
        __builtin_amdgcn_sched_barrier(0);
        if (t + 1 < nt) {
            STAGE((t + 1) & 1, (t + 1) * 32);
            asm volatile("s_waitcnt vmcnt(4)" ::: "memory");
        } else {
            asm volatile("s_waitcnt vmcnt(0)" ::: "memory");
        }
        __builtin_amdgcn_sched_barrier(0);
        const __bf16* as = &As[t & 1][0];
        const __bf16* bs = &Bs[t & 1][0];
        bf16x8 af[4], bfr[4];
#pragma unroll
        for (int i = 0; i < 4; i++) af[i] = *(const bf16x8*)(as + lds_swz(wm + i * 16 + lr, ck));
#pragma unroll
        for (int j = 0; j < 4; j++) bfr[j] = *(const bf16x8*)(bs + lds_swz(wn + j * 16 + lr, ck));
#pragma unroll
        for (int i = 0; i < 4; i++)
#pragma unroll
            for (int j = 0; j < 4; j++) acc[i][j] = MFMA16(af[i], bfr[j], acc[i][j]);
        asm volatile("s_waitcnt lgkmcnt(0)" ::: "memory");
    }
    const int lro = ((tid >> 4) & 3) * 4;
#pragma unroll
    for (int i = 0; i < 4; i++)
#pragma unroll
        for (int j = 0; j < 4; j++) {
            size_t base = (size_t)(seq0 + wm + i * 16 + lro) * 2048 + h * 512 + bn * 128 + wn + j * 16 + lr;
#pragma unroll
            for (int r = 0; r < 4; r++) ob[base + (size_t)r * 2048] = (__bf16)acc[i][j][r];
        }
}

// ---------------- hscan: in-place elementwise scan over 16 chunk slots ----------------
__global__ __launch_bounds__(256) void hscan(__bf16* __restrict__ UH,
                                             const float* __restrict__ ebl) {
    const int t = blockIdx.x * 256 + threadIdx.x;
    const int bh = t >> 14;
    const int rem = t & 16383;
    const int e = rem >> 5, d0 = (rem & 31) * 8;
    float H[8];
#pragma unroll
    for (int j = 0; j < 8; j++) H[j] = 0.f;
    for (int i = 0; i < 16; i++) {
        size_t idx = ((size_t)(i * 16 + bh) * 512 + e) * 256 + d0;
        bf16x8 u = *(const bf16x8*)(UH + idx);
        const float* ep = ebl + (size_t)(i * 16 + bh) * 256 + d0;
        f32x4 e0v = *(const f32x4*)ep;
        f32x4 e1v = *(const f32x4*)(ep + 4);
        bf16x8 hw;
#pragma unroll
        for (int j = 0; j < 4; j++) {
            H[j] = e0v[j] * (H[j] + (float)u[j]);
            hw[j] = (__bf16)H[j];
        }
#pragma unroll
        for (int j = 4; j < 8; j++) {
            H[j] = e1v[j - 4] * (H[j] + (float)u[j]);
            hw[j] = (__bf16)H[j];
        }
        *(bf16x8*)(UH + idx) = hw;
    }
}

// ---------------- RMS norm over dv=512 + SiLU gating ----------------
__global__ __launch_bounds__(256) void rms_gate(const __bf16* __restrict__ ob,
                                                const __bf16* __restrict__ gbuf,
                                                const float* __restrict__ gnw,
                                                __bf16* __restrict__ gated) {
    const int idx = blockIdx.x * 4 + (threadIdx.x >> 6);
    const int seq = idx >> 2, h = idx & 3;
    const int l = threadIdx.x & 63;
    bf16x8 o1 = *(const bf16x8*)(ob + (size_t)seq * 2048 + h * 512 + l * 8);
    float v[8];
    float ms = 0.f;
#pragma unroll
    for (int j = 0; j < 8; j++) {
        v[j] = (float)o1[j];
        ms += v[j] * v[j];
    }
#pragma unroll
    for (int off = 1; off < 64; off <<= 1) ms += __shfl_xor(ms, off);
    const float rinv = rsqrtf(ms * (1.f / 512.f) + 1e-5f);
    bf16x8 gv = *(const bf16x8*)(gbuf + (size_t)seq * 2048 + h * 512 + l * 8);
    const float* gw = gnw + l * 8;
    bf16x8 outv;
#pragma unroll
    for (int j = 0; j < 8; j++) {
        float g = (float)gv[j];
        float sig = 1.f / (1.f + expf(-g));
        outv[j] = (__bf16)(v[j] * rinv * gw[j] * g * sig);
    }
    *(bf16x8*)(gated + (size_t)seq * 2048 + h * 512 + l * 8) = outv;
}

extern "C" void kernel_launch(void* const* d_in, const int* in_sizes, int n_in,
                              void* d_out, int out_size, void* d_ws, size_t ws_size,
                              hipStream_t stream) {
    const float* x = (const float*)d_in[0];
    const float* Wq = (const float*)d_in[1];
    const float* Wk = (const float*)d_in[2];
    const float* Wv = (const float*)d_in[3];
    const float* Wg = (const float*)d_in[4];
    const float* w1 = (const float*)d_in[5];
    const float* w2 = (const float*)d_in[6];
    const float* b2 = (const float*)d_in[7];
    const float* gnw = (const float*)d_in[8];
    const float* Wo = (const float*)d_in[9];
    float* out = (float*)d_out;

    char* p = (char*)d_ws;
    auto nxt = [&](size_t bytes) {
        char* r = p;
        p += (bytes + 255) & ~(size_t)255;
        return r;
    };
    __bf16* xb = (__bf16*)nxt(8192ull * 1024 * 2);
    __bf16* WTqk = (__bf16*)nxt(2048ull * 1024 * 2);
    __bf16* WTg = (__bf16*)nxt(2048ull * 1024 * 2);
    __bf16* WvT = (__bf16*)nxt(2048ull * 1024 * 2);
    __bf16* WoT = (__bf16*)nxt(1024ull * 2048 * 2);
    __bf16* gbuf = (__bf16*)nxt(8192ull * 2048 * 2);
    __bf16* vt = (__bf16*)nxt(2048ull * 8192 * 2);
    float* tbuf = (float*)nxt(8192ull * 16 * 4);
    __bf16* qg = (__bf16*)nxt(8192ull * 1024 * 2);
    __bf16* kgT = (__bf16*)nxt(16ull * 256 * 2048 * 2);
    float* ebl = (float*)nxt(16ull * 16 * 256 * 4);
    __bf16* ob = (__bf16*)nxt(8192ull * 2048 * 2);
    __bf16* UH = (__bf16*)nxt(16ull * 16 * 512 * 256 * 2);
    __bf16* kg = xb;        // alias: xb dead before gate_qkg writes kg
    __bf16* qkbuf = UH;     // alias: dead before amat_chunku writes UH
    __bf16* gated = UH;     // alias: UH dead (read by ointer) before rms_gate writes gated
    __bf16* Abuf = WTqk;    // alias: 8MB = WTqk+WTg, both dead before amat_chunku

    prep<<<10240, 256, 0, stream>>>(x, w1, tbuf, xb, Wq, Wk, Wg, Wv, Wo, WTqk, WTg, WvT, WoT);
    gemm_proj<<<3072, 256, 0, stream>>>(xb, WTqk, WvT, qkbuf, gbuf, vt);
    gate_qkg<<<512, 1024, 0, stream>>>(tbuf, w2, b2, qkbuf, qg, kg, kgT, ebl);
    amat_chunku<<<1280, 512, 0, stream>>>(qg, kg, Abuf, vt, kgT, UH);
    hscan<<<1024, 256, 0, stream>>>(UH, ebl);
    ointer<<<1024, 256, 0, stream>>>(Abuf, qg, vt, UH, ob);
    rms_gate<<<8192, 256, 0, stream>>>(ob, gbuf, gnw, gated);
    gemm_bt<float><<<512, 256, 0, stream>>>(gated, WoT, out, 8192, 1024, 2048);
}